// Round 1
// baseline (183.502 us; speedup 1.0000x reference)
//
#include <hip/hip_runtime.h>

#define NEDGE 625000
#define NNODE 50000
#define APITCH 136  // LDS row pitch in shorts: 128 + 8 pad -> 272 B rows, max 2-way bank aliasing (free)

typedef __bf16 bf16x8 __attribute__((ext_vector_type(8)));
typedef unsigned short u16x8 __attribute__((ext_vector_type(8)));
typedef float f32x4 __attribute__((ext_vector_type(4)));

__device__ __forceinline__ unsigned short f32_bf16(float f) {
  unsigned int u = __float_as_uint(f);
  u += 0x7FFFu + ((u >> 16) & 1u);  // round-to-nearest-even (no NaNs in this problem)
  return (unsigned short)(u >> 16);
}
__device__ __forceinline__ float bf16_f32(unsigned short h) {
  return __uint_as_float(((unsigned int)h) << 16);
}

// ---------------------------------------------------------------------------
// prep: WcatT[j'][k] = W1[k][j'] (j'<128) | W1[128+k][j'-128] (j'>=128), bf16
//       W2T[n][k]    = W2[k][n], bf16
//       idx64_flag   = 1 if edge_index buffer looks like int64 (odd words 0)
// ---------------------------------------------------------------------------
__global__ __launch_bounds__(256) void prep_kernel(
    const float* __restrict__ W1, const float* __restrict__ W2,
    const int* __restrict__ ei,
    unsigned short* __restrict__ WcatT, unsigned short* __restrict__ W2T,
    int* __restrict__ idx64_flag)
{
  int i = blockIdx.x * 256 + threadIdx.x;
  if (i < 256 * 128) {
    int jp = i >> 7, k = i & 127;
    float v = (jp < 128) ? W1[k * 128 + jp] : W1[(128 + k) * 128 + (jp - 128)];
    WcatT[jp * 128 + k] = f32_bf16(v);
  } else if (i < 256 * 128 + 64 * 128) {
    int i2 = i - 256 * 128;
    int n = i2 >> 7, k = i2 & 127;
    W2T[n * 128 + k] = f32_bf16(W2[k * 64 + n]);
  }
  if (i == 0) {
    int allz = 1;
    for (int j = 1; j < 64; j += 2) allz &= (ei[j] == 0);
    *idx64_flag = allz;  // P(false positive with real int32 indices) ~ (1/50000)^32
  }
}

// ---------------------------------------------------------------------------
// uv: UV[n][0:128]   = z[n] @ W1_top + b1   (bf16)
//     UV[n][128:256] = z[n] @ W1_bot        (bf16)
// GEMM M=50000 K=128 N=256, 128-row tiles, N in 4 chunks of 64.
// ---------------------------------------------------------------------------
__global__ __launch_bounds__(256) void uv_kernel(
    const float* __restrict__ z, const float* __restrict__ b1,
    const unsigned short* __restrict__ WcatT,
    unsigned short* __restrict__ UV)
{
  __shared__ unsigned short lA[128 * APITCH];
  __shared__ unsigned short lB[64 * APITCH];
  const int t = threadIdx.x;
  const int r0 = blockIdx.x * 128;

  {  // stage A: 2 threads per row, fp32 -> bf16
    int r = t >> 1, half = t & 1;
    int node = r0 + r;
    unsigned short* dst = &lA[r * APITCH + half * 64];
    if (node < NNODE) {
      const float4* src = (const float4*)(z + (size_t)node * 128 + half * 64);
#pragma unroll
      for (int i = 0; i < 8; ++i) {
        float4 f0 = src[2 * i], f1 = src[2 * i + 1];
        u16x8 o;
        o[0] = f32_bf16(f0.x); o[1] = f32_bf16(f0.y);
        o[2] = f32_bf16(f0.z); o[3] = f32_bf16(f0.w);
        o[4] = f32_bf16(f1.x); o[5] = f32_bf16(f1.y);
        o[6] = f32_bf16(f1.z); o[7] = f32_bf16(f1.w);
        *(u16x8*)(dst + i * 8) = o;
      }
    } else {
      u16x8 zv = {0, 0, 0, 0, 0, 0, 0, 0};
#pragma unroll
      for (int i = 0; i < 8; ++i) *(u16x8*)(dst + i * 8) = zv;
    }
  }

  const int wave = t >> 6, lane = t & 63, c = lane & 15, q = lane >> 4;

  for (int nc = 0; nc < 4; ++nc) {
    if (nc) __syncthreads();  // prior chunk's compute done before overwriting lB
    {  // stage B chunk: rows nc*64 .. nc*64+63 of WcatT
      int n = t >> 2, qd = t & 3;
      const u16x8* src = (const u16x8*)(WcatT + (size_t)(nc * 64 + n) * 128 + qd * 32);
      u16x8* dst = (u16x8*)(&lB[n * APITCH + qd * 32]);
#pragma unroll
      for (int i = 0; i < 4; ++i) dst[i] = src[i];
    }
    __syncthreads();

    f32x4 acc[2][4];
#pragma unroll
    for (int mt = 0; mt < 2; ++mt)
#pragma unroll
      for (int nt = 0; nt < 4; ++nt) {
        f32x4 zz = {0.f, 0.f, 0.f, 0.f};
        acc[mt][nt] = zz;
      }

#pragma unroll
    for (int kt = 0; kt < 4; ++kt) {
      int ko = kt * 32 + q * 8;
      bf16x8 a0 = *(const bf16x8*)(&lA[(wave * 32 + c) * APITCH + ko]);
      bf16x8 a1 = *(const bf16x8*)(&lA[(wave * 32 + 16 + c) * APITCH + ko]);
#pragma unroll
      for (int nt = 0; nt < 4; ++nt) {
        bf16x8 bb = *(const bf16x8*)(&lB[(nt * 16 + c) * APITCH + ko]);
        acc[0][nt] = __builtin_amdgcn_mfma_f32_16x16x32_bf16(a0, bb, acc[0][nt], 0, 0, 0);
        acc[1][nt] = __builtin_amdgcn_mfma_f32_16x16x32_bf16(a1, bb, acc[1][nt], 0, 0, 0);
      }
    }

    // epilogue: fold b1 into cols < 128, store bf16
#pragma unroll
    for (int mt = 0; mt < 2; ++mt) {
      int rbase = r0 + wave * 32 + mt * 16 + q * 4;
#pragma unroll
      for (int nt = 0; nt < 4; ++nt) {
        int col = nc * 64 + nt * 16 + c;
        float badd = (col < 128) ? b1[col] : 0.f;
#pragma unroll
        for (int reg = 0; reg < 4; ++reg) {
          int row = rbase + reg;
          if (row < NNODE)
            UV[(size_t)row * 256 + col] = f32_bf16(acc[mt][nt][reg] + badd);
        }
      }
    }
  }
}

// ---------------------------------------------------------------------------
// edge: per 128-edge tile: h1 = relu(UV[src][0:128] + UV[dst][128:256]) -> LDS
//       h2 = relu(h1 @ W2 + b2) via MFMA; score = h2 @ W3 + b3 (fp32 epilogue)
// ---------------------------------------------------------------------------
__global__ __launch_bounds__(256) void edge_kernel(
    const int* __restrict__ ei,
    const unsigned short* __restrict__ UV,
    const unsigned short* __restrict__ W2T,
    const float* __restrict__ b2, const float* __restrict__ W3,
    const float* __restrict__ b3, const int* __restrict__ idx64_flag,
    float* __restrict__ out)
{
  __shared__ unsigned short lH[128 * APITCH];
  __shared__ unsigned short lW[64 * APITCH];
  const int t = threadIdx.x;
  const int e0 = blockIdx.x * 128;
  const int is64 = *idx64_flag;

  {  // stage W2T (16 KB, reused by all 4 waves)
    int n = t >> 2, qd = t & 3;
    const u16x8* src = (const u16x8*)(W2T + n * 128 + qd * 32);
    u16x8* dst = (u16x8*)(&lW[n * APITCH + qd * 32]);
#pragma unroll
    for (int i = 0; i < 4; ++i) dst[i] = src[i];
  }

  {  // gather + add + relu -> bf16 h1 in LDS (A-fragment friendly layout)
    int r = t >> 1, half = t & 1;
    int e = e0 + r;
    int es = 0, ed = 0;
    if (e < NEDGE) {
      if (is64) {
        es = (int)((const long long*)ei)[e];
        ed = (int)((const long long*)ei)[NEDGE + e];
      } else {
        es = ei[e];
        ed = ei[NEDGE + e];
      }
    }
    const u16x8* su = (const u16x8*)(UV + (size_t)es * 256 + half * 64);
    const u16x8* sv = (const u16x8*)(UV + (size_t)ed * 256 + 128 + half * 64);
    unsigned short* dst = &lH[r * APITCH + half * 64];
#pragma unroll
    for (int i = 0; i < 8; ++i) {
      u16x8 a = su[i], b = sv[i];
      u16x8 o;
#pragma unroll
      for (int j = 0; j < 8; ++j) {
        float f = bf16_f32(a[j]) + bf16_f32(b[j]);  // b1 already folded into U
        o[j] = f32_bf16(fmaxf(f, 0.f));
      }
      *(u16x8*)(dst + i * 8) = o;
    }
  }
  __syncthreads();

  const int wave = t >> 6, lane = t & 63, c = lane & 15, q = lane >> 4;
  f32x4 acc[2][4];
#pragma unroll
  for (int mt = 0; mt < 2; ++mt)
#pragma unroll
    for (int nt = 0; nt < 4; ++nt) {
      f32x4 zz = {0.f, 0.f, 0.f, 0.f};
      acc[mt][nt] = zz;
    }

#pragma unroll
  for (int kt = 0; kt < 4; ++kt) {
    int ko = kt * 32 + q * 8;
    bf16x8 a0 = *(const bf16x8*)(&lH[(wave * 32 + c) * APITCH + ko]);
    bf16x8 a1 = *(const bf16x8*)(&lH[(wave * 32 + 16 + c) * APITCH + ko]);
#pragma unroll
    for (int nt = 0; nt < 4; ++nt) {
      bf16x8 bb = *(const bf16x8*)(&lW[(nt * 16 + c) * APITCH + ko]);
      acc[0][nt] = __builtin_amdgcn_mfma_f32_16x16x32_bf16(a0, bb, acc[0][nt], 0, 0, 0);
      acc[1][nt] = __builtin_amdgcn_mfma_f32_16x16x32_bf16(a1, bb, acc[1][nt], 0, 0, 0);
    }
  }

  // layer 2 bias+relu and layer 3 dot, all fp32 (no bf16 rounding of h2)
  float b2v[4], w3v[4];
#pragma unroll
  for (int nt = 0; nt < 4; ++nt) {
    int n = nt * 16 + c;
    b2v[nt] = b2[n];
    w3v[nt] = W3[n];
  }
  float bias3 = b3[0];

#pragma unroll
  for (int mt = 0; mt < 2; ++mt) {
    float p0 = 0.f, p1 = 0.f, p2 = 0.f, p3 = 0.f;
#pragma unroll
    for (int nt = 0; nt < 4; ++nt) {
      p0 += fmaxf(acc[mt][nt][0] + b2v[nt], 0.f) * w3v[nt];
      p1 += fmaxf(acc[mt][nt][1] + b2v[nt], 0.f) * w3v[nt];
      p2 += fmaxf(acc[mt][nt][2] + b2v[nt], 0.f) * w3v[nt];
      p3 += fmaxf(acc[mt][nt][3] + b2v[nt], 0.f) * w3v[nt];
    }
    // reduce over the 16 column-lanes (c); masks < 16 stay within the quad group
#pragma unroll
    for (int m = 1; m < 16; m <<= 1) {
      p0 += __shfl_xor(p0, m, 64);
      p1 += __shfl_xor(p1, m, 64);
      p2 += __shfl_xor(p2, m, 64);
      p3 += __shfl_xor(p3, m, 64);
    }
    if (c == 0) {
      int eb = e0 + wave * 32 + mt * 16 + q * 4;
      if (eb + 0 < NEDGE) out[eb + 0] = p0 + bias3;
      if (eb + 1 < NEDGE) out[eb + 1] = p1 + bias3;
      if (eb + 2 < NEDGE) out[eb + 2] = p2 + bias3;
      if (eb + 3 < NEDGE) out[eb + 3] = p3 + bias3;
    }
  }
}

extern "C" void kernel_launch(void* const* d_in, const int* in_sizes, int n_in,
                              void* d_out, int out_size, void* d_ws, size_t ws_size,
                              hipStream_t stream) {
  const float* z  = (const float*)d_in[0];
  const int*   ei = (const int*)d_in[1];
  const float* W1 = (const float*)d_in[2];
  const float* b1 = (const float*)d_in[3];
  const float* W2 = (const float*)d_in[4];
  const float* b2 = (const float*)d_in[5];
  const float* W3 = (const float*)d_in[6];
  const float* b3 = (const float*)d_in[7];
  float* out = (float*)d_out;

  // workspace layout (25.7 MB total)
  unsigned short* UV    = (unsigned short*)d_ws;   // 50000*256 bf16 = 25.6 MB
  unsigned short* WcatT = UV + (size_t)NNODE * 256;  // 256*128 bf16
  unsigned short* W2T   = WcatT + 256 * 128;         // 64*128 bf16
  int* idx64_flag       = (int*)(W2T + 64 * 128);

  prep_kernel<<<dim3(160), dim3(256), 0, stream>>>(W1, W2, ei, WcatT, W2T, idx64_flag);
  uv_kernel<<<dim3((NNODE + 127) / 128), dim3(256), 0, stream>>>(z, b1, WcatT, UV);
  edge_kernel<<<dim3((NEDGE + 127) / 128), dim3(256), 0, stream>>>(
      ei, UV, W2T, b2, W3, b3, idx64_flag, out);
}

// Round 3
// 153.580 us; speedup vs baseline: 1.1948x; 1.1948x over previous
//
#include <hip/hip_runtime.h>

#define NEDGE 625000
#define NNODE 50000
#define WPITCH 136  // lW pitch in shorts: 272 B rows -> 2-way bank aliasing on b128 (free)
#define EPITCH 68   // uv epilogue pitch in shorts

typedef __bf16 bf16x8 __attribute__((ext_vector_type(8)));
typedef unsigned short u16x8 __attribute__((ext_vector_type(8)));
typedef float f32x4 __attribute__((ext_vector_type(4)));

__device__ __forceinline__ unsigned short f32_bf16(float f) {
  unsigned int u = __float_as_uint(f);
  u += 0x7FFFu + ((u >> 16) & 1u);  // RNE (no NaNs in this problem)
  return (unsigned short)(u >> 16);
}
__device__ __forceinline__ float bf16_f32(unsigned short h) {
  return __uint_as_float(((unsigned int)h) << 16);
}

// ---------------------------------------------------------------------------
// prep: WcatT[j'][k] = W1[k][j'] (j'<128) | W1[128+k][j'-128], bf16
//       W2T[n][k]    = W2[k][n], bf16
//       idx64_flag   = 1 if edge_index buffer looks like int64 (odd words 0)
// ---------------------------------------------------------------------------
__global__ __launch_bounds__(256) void prep_kernel(
    const float* __restrict__ W1, const float* __restrict__ W2,
    const int* __restrict__ ei,
    unsigned short* __restrict__ WcatT, unsigned short* __restrict__ W2T,
    int* __restrict__ idx64_flag)
{
  int i = blockIdx.x * 256 + threadIdx.x;
  if (i < 256 * 128) {
    int jp = i >> 7, k = i & 127;
    float v = (jp < 128) ? W1[k * 128 + jp] : W1[(128 + k) * 128 + (jp - 128)];
    WcatT[jp * 128 + k] = f32_bf16(v);
  } else if (i < 256 * 128 + 64 * 128) {
    int i2 = i - 256 * 128;
    int n = i2 >> 7, k = i2 & 127;
    W2T[n * 128 + k] = f32_bf16(W2[k * 64 + n]);
  }
  if (i == 0) {
    int allz = 1;
    for (int j = 1; j < 64; j += 2) allz &= (ei[j] == 0);
    *idx64_flag = allz;
  }
}

// ---------------------------------------------------------------------------
// uv: UV[n][0:128] = z[n]@W1_top + b1, UV[n][128:256] = z[n]@W1_bot  (bf16)
// Barrier-free: A-frags direct from fp32 z, B-frags direct from L2-hot WcatT,
// epilogue transposed through per-wave private LDS for dwordx4 stores.
// ---------------------------------------------------------------------------
__global__ __launch_bounds__(256) void uv_kernel(
    const float* __restrict__ z, const float* __restrict__ b1,
    const unsigned short* __restrict__ WcatT,
    unsigned short* __restrict__ UV)
{
  __shared__ unsigned short st[4 * 32 * EPITCH];
  const int t = threadIdx.x, wave = t >> 6, lane = t & 63, c = lane & 15, q = lane >> 4;
  const int mbase = blockIdx.x * 128 + wave * 32;
  const int rA = mbase + c, rB = mbase + 16 + c;
  const int rAc = (rA < NNODE) ? rA : 0;
  const int rBc = (rB < NNODE) ? rB : 0;

  // A-fragments: 8 fp32 each at z[row][kt*32+q*8], convert to bf16 in regs
  bf16x8 a0[4], a1[4];
  {
    const float* zA = z + (size_t)rAc * 128 + q * 8;
    const float* zB = z + (size_t)rBc * 128 + q * 8;
    float4 fA[4][2], fB[4][2];
#pragma unroll
    for (int kt = 0; kt < 4; ++kt) {
      fA[kt][0] = ((const float4*)(zA + kt * 32))[0];
      fA[kt][1] = ((const float4*)(zA + kt * 32))[1];
      fB[kt][0] = ((const float4*)(zB + kt * 32))[0];
      fB[kt][1] = ((const float4*)(zB + kt * 32))[1];
    }
#pragma unroll
    for (int kt = 0; kt < 4; ++kt) {
      const float* pa = (const float*)&fA[kt][0];
      const float* pb = (const float*)&fB[kt][0];
      u16x8 oa, ob;
#pragma unroll
      for (int j = 0; j < 8; ++j) { oa[j] = f32_bf16(pa[j]); ob[j] = f32_bf16(pb[j]); }
      a0[kt] = *(bf16x8*)&oa;
      a1[kt] = *(bf16x8*)&ob;
    }
  }

  unsigned short* my = &st[wave * 32 * EPITCH];

  for (int nc = 0; nc < 4; ++nc) {
    f32x4 acc[2][4];
#pragma unroll
    for (int mt = 0; mt < 2; ++mt)
#pragma unroll
      for (int nt = 0; nt < 4; ++nt) {
        f32x4 zz = {0.f, 0.f, 0.f, 0.f};
        acc[mt][nt] = zz;
      }

#pragma unroll
    for (int kt = 0; kt < 4; ++kt) {
#pragma unroll
      for (int nt = 0; nt < 4; ++nt) {
        bf16x8 bb = *(const bf16x8*)(WcatT + (size_t)(nc * 64 + nt * 16 + c) * 128 + kt * 32 + q * 8);
        acc[0][nt] = __builtin_amdgcn_mfma_f32_16x16x32_bf16(a0[kt], bb, acc[0][nt], 0, 0, 0);
        acc[1][nt] = __builtin_amdgcn_mfma_f32_16x16x32_bf16(a1[kt], bb, acc[1][nt], 0, 0, 0);
      }
    }

    float badd[4];
#pragma unroll
    for (int nt = 0; nt < 4; ++nt) {
      int col = nc * 64 + nt * 16 + c;
      badd[nt] = (col < 128) ? b1[col] : 0.f;
    }

    // stage C-chunk (32 rows x 64 cols = 2048 shorts) in wave-private LDS
#pragma unroll
    for (int mt = 0; mt < 2; ++mt)
#pragma unroll
      for (int nt = 0; nt < 4; ++nt)
#pragma unroll
        for (int reg = 0; reg < 4; ++reg)
          my[(mt * 16 + q * 4 + reg) * EPITCH + nt * 16 + c] =
              f32_bf16(acc[mt][nt][reg] + badd[nt]);
    __asm__ volatile("s_waitcnt lgkmcnt(0)" ::: "memory");

    // vectorized store: each lane takes 32 shorts (64 B): row lrow, cols [half*32, half*32+32)
    {
      int lrow = lane >> 1, half = lane & 1;
      int grow = mbase + lrow;
      u16x8 d0 = *(u16x8*)&my[lrow * EPITCH + half * 32 + 0];
      u16x8 d1 = *(u16x8*)&my[lrow * EPITCH + half * 32 + 8];
      u16x8 d2 = *(u16x8*)&my[lrow * EPITCH + half * 32 + 16];
      u16x8 d3 = *(u16x8*)&my[lrow * EPITCH + half * 32 + 24];
      if (grow < NNODE) {
        u16x8* dst = (u16x8*)(UV + (size_t)grow * 256 + nc * 64 + half * 32);
        dst[0] = d0;
        dst[1] = d1;
        dst[2] = d2;
        dst[3] = d3;
      }
    }
    __asm__ volatile("s_waitcnt lgkmcnt(0)" ::: "memory");  // reads drain before next chunk overwrites
  }
}

// ---------------------------------------------------------------------------
// edge: gather MFMA A-frags DIRECTLY from UV (no h1 LDS, no gather barrier):
// lane (c,q) reads 16B granules of rows src/dst; add+relu in regs -> frags.
// h2 = relu(h1@W2+b2) via MFMA (W2T staged once in LDS); score fp32 epilogue.
// ---------------------------------------------------------------------------
__global__ __launch_bounds__(256) void edge_kernel(
    const int* __restrict__ ei,
    const unsigned short* __restrict__ UV,
    const unsigned short* __restrict__ W2T,
    const float* __restrict__ b2, const float* __restrict__ W3,
    const float* __restrict__ b3, const int* __restrict__ idx64_flag,
    float* __restrict__ out)
{
  __shared__ unsigned short lW[64 * WPITCH];
  const int t = threadIdx.x, wave = t >> 6, lane = t & 63, c = lane & 15, q = lane >> 4;

  {  // stage W2T once (16 KB shared by all waves)
    int n = t >> 2, qd = t & 3;
    const u16x8* src = (const u16x8*)(W2T + n * 128 + qd * 32);
    u16x8* dst = (u16x8*)(&lW[n * WPITCH + qd * 32]);
#pragma unroll
    for (int i = 0; i < 4; ++i) dst[i] = src[i];
  }
  __syncthreads();  // the only barrier in this kernel

  const int ebase = blockIdx.x * 128 + wave * 32;
  const int eA = ebase + c, eB = ebase + 16 + c;
  const int eAc = (eA < NEDGE) ? eA : 0;
  const int eBc = (eB < NEDGE) ? eB : 0;
  int sA, dA, sB, dB;
  if (*idx64_flag) {
    const long long* e64 = (const long long*)ei;
    sA = (int)e64[eAc]; dA = (int)e64[NEDGE + eAc];
    sB = (int)e64[eBc]; dB = (int)e64[NEDGE + eBc];
  } else {
    sA = ei[eAc]; dA = ei[NEDGE + eAc];
    sB = ei[eBc]; dB = ei[NEDGE + eBc];
  }

  // 16 independent 16B gather loads (4 per kt): U-half of src, V-half of dst
  const u16x8* pAu = (const u16x8*)(UV + (size_t)sA * 256) + q;
  const u16x8* pAv = (const u16x8*)(UV + (size_t)dA * 256 + 128) + q;
  const u16x8* pBu = (const u16x8*)(UV + (size_t)sB * 256) + q;
  const u16x8* pBv = (const u16x8*)(UV + (size_t)dB * 256 + 128) + q;
  u16x8 rAu[4], rAv[4], rBu[4], rBv[4];
#pragma unroll
  for (int kt = 0; kt < 4; ++kt) {
    rAu[kt] = pAu[kt * 4];
    rAv[kt] = pAv[kt * 4];
    rBu[kt] = pBu[kt * 4];
    rBv[kt] = pBv[kt * 4];
  }

  f32x4 acc[2][4];
#pragma unroll
  for (int mt = 0; mt < 2; ++mt)
#pragma unroll
    for (int nt = 0; nt < 4; ++nt) {
      f32x4 zz = {0.f, 0.f, 0.f, 0.f};
      acc[mt][nt] = zz;
    }

#pragma unroll
  for (int kt = 0; kt < 4; ++kt) {
    u16x8 oa, ob;
#pragma unroll
    for (int j = 0; j < 8; ++j) {
      oa[j] = f32_bf16(fmaxf(bf16_f32(rAu[kt][j]) + bf16_f32(rAv[kt][j]), 0.f));
      ob[j] = f32_bf16(fmaxf(bf16_f32(rBu[kt][j]) + bf16_f32(rBv[kt][j]), 0.f));
    }
    bf16x8 a0 = *(bf16x8*)&oa;
    bf16x8 a1 = *(bf16x8*)&ob;
#pragma unroll
    for (int nt = 0; nt < 4; ++nt) {
      bf16x8 bb = *(const bf16x8*)(&lW[(nt * 16 + c) * WPITCH + kt * 32 + q * 8]);
      acc[0][nt] = __builtin_amdgcn_mfma_f32_16x16x32_bf16(a0, bb, acc[0][nt], 0, 0, 0);
      acc[1][nt] = __builtin_amdgcn_mfma_f32_16x16x32_bf16(a1, bb, acc[1][nt], 0, 0, 0);
    }
  }

  // layer-2 bias+relu and layer-3 dot in fp32; reduce over the 16 c-lanes
  float b2v[4], w3v[4];
#pragma unroll
  for (int nt = 0; nt < 4; ++nt) {
    int n = nt * 16 + c;
    b2v[nt] = b2[n];
    w3v[nt] = W3[n];
  }
  float bias3 = b3[0];

#pragma unroll
  for (int mt = 0; mt < 2; ++mt) {
    float p0 = 0.f, p1 = 0.f, p2 = 0.f, p3 = 0.f;
#pragma unroll
    for (int nt = 0; nt < 4; ++nt) {
      p0 += fmaxf(acc[mt][nt][0] + b2v[nt], 0.f) * w3v[nt];
      p1 += fmaxf(acc[mt][nt][1] + b2v[nt], 0.f) * w3v[nt];
      p2 += fmaxf(acc[mt][nt][2] + b2v[nt], 0.f) * w3v[nt];
      p3 += fmaxf(acc[mt][nt][3] + b2v[nt], 0.f) * w3v[nt];
    }
#pragma unroll
    for (int m = 1; m < 16; m <<= 1) {
      p0 += __shfl_xor(p0, m, 64);
      p1 += __shfl_xor(p1, m, 64);
      p2 += __shfl_xor(p2, m, 64);
      p3 += __shfl_xor(p3, m, 64);
    }
    if (c == 0) {
      int eb = ebase + mt * 16 + q * 4;
      if (eb + 0 < NEDGE) out[eb + 0] = p0 + bias3;
      if (eb + 1 < NEDGE) out[eb + 1] = p1 + bias3;
      if (eb + 2 < NEDGE) out[eb + 2] = p2 + bias3;
      if (eb + 3 < NEDGE) out[eb + 3] = p3 + bias3;
    }
  }
}

extern "C" void kernel_launch(void* const* d_in, const int* in_sizes, int n_in,
                              void* d_out, int out_size, void* d_ws, size_t ws_size,
                              hipStream_t stream) {
  const float* z  = (const float*)d_in[0];
  const int*   ei = (const int*)d_in[1];
  const float* W1 = (const float*)d_in[2];
  const float* b1 = (const float*)d_in[3];
  const float* W2 = (const float*)d_in[4];
  const float* b2 = (const float*)d_in[5];
  const float* W3 = (const float*)d_in[6];
  const float* b3 = (const float*)d_in[7];
  float* out = (float*)d_out;

  unsigned short* UV    = (unsigned short*)d_ws;       // 50000*256 bf16 = 25.6 MB
  unsigned short* WcatT = UV + (size_t)NNODE * 256;    // 256*128 bf16
  unsigned short* W2T   = WcatT + 256 * 128;           // 64*128 bf16
  int* idx64_flag       = (int*)(W2T + 64 * 128);

  prep_kernel<<<dim3(160), dim3(256), 0, stream>>>(W1, W2, ei, WcatT, W2T, idx64_flag);
  uv_kernel<<<dim3((NNODE + 127) / 128), dim3(256), 0, stream>>>(z, b1, WcatT, UV);
  edge_kernel<<<dim3((NEDGE + 127) / 128), dim3(256), 0, stream>>>(
      ei, UV, W2T, b2, W3, b3, idx64_flag, out);
}